// Round 16
// baseline (148.617 us; speedup 1.0000x reference)
//
#include <hip/hip_runtime.h>

typedef __fp16   fp16x2  __attribute__((ext_vector_type(2)));
typedef _Float16 half4   __attribute__((ext_vector_type(4)));
typedef float    floatx2 __attribute__((ext_vector_type(2)));
typedef float    floatx4 __attribute__((ext_vector_type(4)));

__device__ __forceinline__ floatx2 exp2p(floatx2 a) {
    floatx2 r = { __builtin_amdgcn_exp2f(a[0]), __builtin_amdgcn_exp2f(a[1]) };
    return r;
}

// Paired r-act (net1/net2) packed across channel-streams A/B, ONE rcp for all
// four denominators (Montgomery-4): p=d1*d2; q=rcp(pA*pB); qv=q*swap(p);
// r1=qv*d2; r2=qv*d1. Ranges: products <= 2^116 < inf.
__device__ __forceinline__ void ract4p(floatx2 a1, floatx2 a2,
                                       floatx2* r1, floatx2* r2) {
    floatx2 d1 = exp2p(a1) + 1.0f;
    floatx2 d2 = exp2p(a2) + 1.0f;
    floatx2 p  = d1 * d2;
    float   q  = __builtin_amdgcn_rcpf(p[0] * p[1]);
    floatx2 qv = q * __builtin_shufflevector(p, p, 1, 0);
    *r1 = qv * d2;
    *r2 = qv * d1;
}
// L3 difference variant: r1 - r2 = qv*(d2 - d1).
__device__ __forceinline__ floatx2 ract4d(floatx2 a1, floatx2 a2) {
    floatx2 d1 = exp2p(a1) + 1.0f;
    floatx2 d2 = exp2p(a2) + 1.0f;
    floatx2 p  = d1 * d2;
    float   q  = __builtin_amdgcn_rcpf(p[0] * p[1]);
    floatx2 qv = q * __builtin_shufflevector(p, p, 1, 0);
    return qv * (d2 - d1);
}

__device__ __forceinline__ half4 mk4f(floatx4 v) {
    fp16x2 lo = __builtin_amdgcn_cvt_pkrtz(v[0], v[1]);
    fp16x2 hi = __builtin_amdgcn_cvt_pkrtz(v[2], v[3]);
    union { fp16x2 h2[2]; half4 h4; } u;
    u.h2[0] = lo; u.h2[1] = hi;
    return u.h4;
}

__global__ __launch_bounds__(256, 8) void automaton_kernel(
    const float* __restrict__ x, const float* __restrict__ Ws,
    const float* __restrict__ bs, const float* __restrict__ Wf,
    const float* __restrict__ bf, const float* __restrict__ extra,
    float* __restrict__ out, int n_groups)
{
    const float K = 2.885390081777927f;  // 2*log2(e)
    const int tid   = blockIdx.x * blockDim.x + threadIdx.x;
    const int wave  = tid >> 6;
    const int lane  = threadIdx.x & 63;
    const int col   = lane & 15;
    const int sub   = lane >> 4;
    const int obase = sub * 4;

    const floatx4 zeroC = {0.f, 0.f, 0.f, 0.f};
    const half4   ones  = {(_Float16)1.f, (_Float16)1.f, (_Float16)1.f, (_Float16)1.f};
    const half4   hzero = {(_Float16)0.f, (_Float16)0.f, (_Float16)0.f, (_Float16)0.f};

    float ex[12];
#pragma unroll
    for (int j = 0; j < 12; ++j) ex[j] = extra[j];

    // ---- Layer 0 as MFMA: A-frag = f16(K*W0[col][obase+e]); rows 4..15 of B
    // are constants folded into c1C = K*(b0 + W0[:,4:16].extra); only B-rows
    // 0..3 (x) are fed via sub==0 lanes.
    // net2's rotated input is absorbed into a SECOND A-frag with the live
    // columns permuted (A2[o,k] = W0[o,rot(k)]): B-columns 4..15 are zero so
    // only elements 0..3 matter, and for sub==0 lanes rot = (2,3,0,1).
    half4 aL0, aL0r;
    floatx4 c1C;
    {
        floatx4 w0r = *(const floatx4*)(Ws + col * 16 + obase);
#pragma unroll
        for (int e = 0; e < 4; ++e) aL0[e] = (_Float16)(w0r[e] * K);
        aL0r = (sub == 0) ? __builtin_shufflevector(aL0, aL0, 2, 3, 0, 1) : aL0;
#pragma unroll
        for (int e = 0; e < 4; ++e) {
            const float* row = Ws + (obase + e) * 16;
            floatx4 r1 = *(const floatx4*)(row + 4);
            floatx4 r2 = *(const floatx4*)(row + 8);
            floatx4 r3 = *(const floatx4*)(row + 12);
            float c = bs[obase + e];
#pragma unroll
            for (int j = 0; j < 4; ++j) c = fmaf(r1[j], ex[j], c);
#pragma unroll
            for (int j = 0; j < 4; ++j) c = fmaf(r2[j], ex[4 + j], c);
#pragma unroll
            for (int j = 0; j < 4; ++j) c = fmaf(r3[j], ex[8 + j], c);
            c1C[e] = c * K;
        }
    }

    // ---- Hidden layers 1..3: A'' = f16(-2K*W); c'' = K*b - 0.5*(A''.1) ----
    half4 aW0, aW1, aW2, aWf;
    floatx4 bC0, bC1, bC2;
    {
        floatx4 w1 = *(const floatx4*)(Ws + 256 + col * 16 + obase);
        floatx4 w2 = *(const floatx4*)(Ws + 512 + col * 16 + obase);
        floatx4 w3 = *(const floatx4*)(Ws + 768 + col * 16 + obase);
#pragma unroll
        for (int e = 0; e < 4; ++e) {
            aW0[e] = (_Float16)(w1[e] * (-2.0f * K));
            aW1[e] = (_Float16)(w2[e] * (-2.0f * K));
            aW2[e] = (_Float16)(w3[e] * (-2.0f * K));
        }
        floatx4 s0 = __builtin_amdgcn_mfma_f32_16x16x16f16(aW0, ones, zeroC, 0, 0, 0);
        floatx4 s1 = __builtin_amdgcn_mfma_f32_16x16x16f16(aW1, ones, zeroC, 0, 0, 0);
        floatx4 s2 = __builtin_amdgcn_mfma_f32_16x16x16f16(aW2, ones, zeroC, 0, 0, 0);
        floatx4 b1 = *(const floatx4*)(bs + 16 + obase);
        floatx4 b2 = *(const floatx4*)(bs + 32 + obase);
        floatx4 b3 = *(const floatx4*)(bs + 48 + obase);
#pragma unroll
        for (int e = 0; e < 4; ++e) {
            bC0[e] = fmaf(-0.5f, s0[e], K * b1[e]);
            bC1[e] = fmaf(-0.5f, s1[e], K * b2[e]);
            bC2[e] = fmaf(-0.5f, s2[e], K * b3[e]);
        }
        floatx4 wf = *(const floatx4*)(Wf + obase);
#pragma unroll
        for (int e = 0; e < 4; ++e) aWf[e] = (_Float16)(wf[e] * (-2.0f * K));
    }

    const int g      = wave * 16 + col;
    const bool valid = (g < n_groups);
    const int gl     = valid ? g : (n_groups - 1);
    const float* xp  = x + (size_t)gl * 104;   // 26 channels * 4 floats
    const bool sub0  = (sub == 0);

    // Accumulate Sum(r_final) only; tanh = 1-2r is folded into the output
    // write: out = (26 - 2*Sum(r)) * scale.
    floatx2 accp = {0.f, 0.f};
#pragma unroll 1
    for (int c = 0; c < 13; ++c) {
        // Two independent channel streams: A=c, B=c+13.
        floatx4 xvA = *(const floatx4*)(xp + c * 4);
        floatx4 xvB = *(const floatx4*)(xp + (c + 13) * 4);
        // x as the L0 B-fragment (packed RTZ converts), zero off sub==0.
        half4 hxA = sub0 ? mk4f(xvA) : hzero;
        half4 hxB = sub0 ? mk4f(xvB) : hzero;

        // ---- Layer 0 via MFMA: net2 uses the pre-rotated A-frag ----
        floatx4 dA1 = __builtin_amdgcn_mfma_f32_16x16x16f16(aL0,  hxA, c1C, 0, 0, 0);
        floatx4 dA2 = __builtin_amdgcn_mfma_f32_16x16x16f16(aL0r, hxA, c1C, 0, 0, 0);
        floatx4 dB1 = __builtin_amdgcn_mfma_f32_16x16x16f16(aL0,  hxB, c1C, 0, 0, 0);
        floatx4 dB2 = __builtin_amdgcn_mfma_f32_16x16x16f16(aL0r, hxB, c1C, 0, 0, 0);

        floatx4 rA1, rA2, rB1, rB2;
#pragma unroll
        for (int e = 0; e < 4; ++e) {
            floatx2 p1 = {dA1[e], dB1[e]};
            floatx2 p2 = {dA2[e], dB2[e]};
            floatx2 r1p, r2p;
            ract4p(p1, p2, &r1p, &r2p);
            rA1[e] = r1p[0]; rB1[e] = r1p[1];
            rA2[e] = r2p[0]; rB2[e] = r2p[1];
        }
        half4 hA1 = mk4f(rA1), hA2 = mk4f(rA2);
        half4 hB1 = mk4f(rB1), hB2 = mk4f(rB2);

        // ---- Hidden layer 1 ----
        {
            floatx4 e1 = __builtin_amdgcn_mfma_f32_16x16x16f16(aW0, hA1, bC0, 0, 0, 0);
            floatx4 e2 = __builtin_amdgcn_mfma_f32_16x16x16f16(aW0, hA2, bC0, 0, 0, 0);
            floatx4 e3 = __builtin_amdgcn_mfma_f32_16x16x16f16(aW0, hB1, bC0, 0, 0, 0);
            floatx4 e4 = __builtin_amdgcn_mfma_f32_16x16x16f16(aW0, hB2, bC0, 0, 0, 0);
#pragma unroll
            for (int e = 0; e < 4; ++e) {
                floatx2 p1 = {e1[e], e3[e]};
                floatx2 p2 = {e2[e], e4[e]};
                floatx2 r1p, r2p;
                ract4p(p1, p2, &r1p, &r2p);
                rA1[e] = r1p[0]; rB1[e] = r1p[1];
                rA2[e] = r2p[0]; rB2[e] = r2p[1];
            }
            hA1 = mk4f(rA1); hA2 = mk4f(rA2);
            hB1 = mk4f(rB1); hB2 = mk4f(rB2);
        }
        // ---- Hidden layer 2 ----
        {
            floatx4 e1 = __builtin_amdgcn_mfma_f32_16x16x16f16(aW1, hA1, bC1, 0, 0, 0);
            floatx4 e2 = __builtin_amdgcn_mfma_f32_16x16x16f16(aW1, hA2, bC1, 0, 0, 0);
            floatx4 e3 = __builtin_amdgcn_mfma_f32_16x16x16f16(aW1, hB1, bC1, 0, 0, 0);
            floatx4 e4 = __builtin_amdgcn_mfma_f32_16x16x16f16(aW1, hB2, bC1, 0, 0, 0);
#pragma unroll
            for (int e = 0; e < 4; ++e) {
                floatx2 p1 = {e1[e], e3[e]};
                floatx2 p2 = {e2[e], e4[e]};
                floatx2 r1p, r2p;
                ract4p(p1, p2, &r1p, &r2p);
                rA1[e] = r1p[0]; rB1[e] = r1p[1];
                rA2[e] = r2p[0]; rB2[e] = r2p[1];
            }
            hA1 = mk4f(rA1); hA2 = mk4f(rA2);
            hB1 = mk4f(rB1); hB2 = mk4f(rB2);
        }
        // ---- Hidden layer 3 + fused final 16->1 (only r1-r2 needed) ----
        {
            floatx4 e1 = __builtin_amdgcn_mfma_f32_16x16x16f16(aW2, hA1, bC2, 0, 0, 0);
            floatx4 e2 = __builtin_amdgcn_mfma_f32_16x16x16f16(aW2, hA2, bC2, 0, 0, 0);
            floatx4 e3 = __builtin_amdgcn_mfma_f32_16x16x16f16(aW2, hB1, bC2, 0, 0, 0);
            floatx4 e4 = __builtin_amdgcn_mfma_f32_16x16x16f16(aW2, hB2, bC2, 0, 0, 0);
            floatx4 sAv, sBv;
#pragma unroll
            for (int e = 0; e < 4; ++e) {
                floatx2 p1 = {e1[e], e3[e]};
                floatx2 p2 = {e2[e], e4[e]};
                floatx2 sp = ract4d(p1, p2);
                sAv[e] = sp[0]; sBv[e] = sp[1];
            }
            half4 sA = mk4f(sAv);
            half4 sB = mk4f(sBv);
            floatx4 drA = __builtin_amdgcn_mfma_f32_16x16x16f16(aWf, sA, zeroC, 0, 0, 0);
            floatx4 drB = __builtin_amdgcn_mfma_f32_16x16x16f16(aWf, sB, zeroC, 0, 0, 0);
            // Final act: accumulate r only (Montgomery-2 across {A,B}).
            floatx2 drp = {drA[0], drB[0]};
            floatx2 dd  = exp2p(drp) + 1.0f;
            float   qq  = __builtin_amdgcn_rcpf(dd[0] * dd[1]);
            accp += qq * __builtin_shufflevector(dd, dd, 1, 0);
        }
    }
    if (lane < 16 && valid) {
        const float S = 0.041875863808787856f;  // ONE_OVER_DIFF_TOT * DIFF_Q
        out[g] = fmaf(-2.0f * S, accp[0] + accp[1], 26.0f * S);
    }
}

extern "C" void kernel_launch(void* const* d_in, const int* in_sizes, int n_in,
                              void* d_out, int out_size, void* d_ws, size_t ws_size,
                              hipStream_t stream) {
    const float* x  = (const float*)d_in[0];
    const float* Ws = (const float*)d_in[1];
    const float* bs = (const float*)d_in[2];
    const float* Wf = (const float*)d_in[3];
    const float* bf = (const float*)d_in[4];
    const float* ex = (const float*)d_in[5];
    float* out = (float*)d_out;

    const int n_groups = out_size;              // B*N = 262144
    const int waves    = (n_groups + 15) / 16;  // 16 groups per wave
    const int blocks   = (waves + 3) / 4;       // 4 waves per block
    automaton_kernel<<<blocks, 256, 0, stream>>>(x, Ws, bs, Wf, bf, ex, out, n_groups);
}